// Round 6
// baseline (797.294 us; speedup 1.0000x reference)
//
#include <hip/hip_runtime.h>
#include <hip/hip_fp16.h>
#include <math.h>
#include <stdint.h>

#define Bb 8
#define Ss 512
#define Dd 768
#define Hh 12
#define Ee 8
#define DFF 3072
#define MROWS 4096          // B*S
#define QKVN 2304           // H*3*DH

static __device__ const float SCALE_ = 0.036084391824351615f; // 768^-0.5
static __device__ const float SC2_   = 0.05206262648008056f;  // 768^-0.5 * log2(e)

typedef short bf8_t __attribute__((ext_vector_type(8)));
typedef _Float16 f16x4_t __attribute__((ext_vector_type(4)));
typedef float f32x4_t __attribute__((ext_vector_type(4)));

__device__ __forceinline__ float bf2f(unsigned short u){
  union { unsigned int i; float f; } x; x.i = ((unsigned int)u)<<16; return x.f;
}
__device__ __forceinline__ unsigned short f2bf(float f){
  union { float f; unsigned int i; } x; x.f = f;
  unsigned int u = x.i;
  return (unsigned short)((u + 0x7fffu + ((u>>16)&1u)) >> 16);
}

// async global->LDS, 16B per lane; LDS dest is wave-uniform base + lane*16
__device__ __forceinline__ void gl_lds16(const void* g, void* l){
  __builtin_amdgcn_global_load_lds(
      (const __attribute__((address_space(1))) unsigned int*)(g),
      (__attribute__((address_space(3))) unsigned int*)(uintptr_t)(l),
      16, 0, 0);
}

// ---------------- cast fp32 -> bf16 (n % 4 == 0) ----------------
__global__ void cast_kernel(const float* __restrict__ in, unsigned short* __restrict__ out, int n){
  int i = (blockIdx.x*256 + threadIdx.x)*4;
  if (i >= n) return;
  const float4 v = *(const float4*)(in + i);
  ushort4 o; o.x=f2bf(v.x); o.y=f2bf(v.y); o.z=f2bf(v.z); o.w=f2bf(v.w);
  *(ushort4*)(out + i) = o;
}

// =====================================================================================
// 256x256 tile, 8-wave, 8-phase pipelined bf16 GEMM: C = A(MxK) * B(NxK)^T  (QKV)
// R6: R5's B-fragment register cache, with __launch_bounds__(512) (no min-waves cap).
// Occupancy is LDS-bound at 1 block/CU = 2 waves/SIMD either way; the 2-waves/EU
// declaration capped VGPR at 128 and forced in-loop scratch spills (R5: WRITE +43MB,
// MfmaUtil 35->29.6). Uncapped (<=256 VGPR for an 8-wave block) removes the spills.
// =====================================================================================
#define VMW6 asm volatile("s_waitcnt vmcnt(6)" ::: "memory")
#define VMW0 asm volatile("s_waitcnt vmcnt(0)" ::: "memory")
#define NOOP ((void)0)

#define STG_A(SL,H,KT) { char* d_ = smem + (SL)*32768 + (H)*16384 + w*1024;          \
    gl_lds16(aSrc[0] + (size_t)(H)*hK + (size_t)(KT)*64, d_);                        \
    gl_lds16(aSrc[1] + (size_t)(H)*hK + (size_t)(KT)*64, d_ + 8192); }
#define STG_B(SL,H,KT) { char* d_ = smem + 65536 + (SL)*32768 + (H)*16384 + w*1024;  \
    gl_lds16(bSrc[0] + (size_t)(H)*hK + (size_t)(KT)*64, d_);                        \
    gl_lds16(bSrc[1] + (size_t)(H)*hK + (size_t)(KT)*64, d_ + 8192); }

#define PHASE(SL, QM, QN, DO_A, DO_B, STAGE, WAITC)                                  \
  {                                                                                  \
    STAGE;                                                                           \
    WAITC;                                                                           \
    __builtin_amdgcn_s_barrier();                                                    \
    asm volatile("" ::: "memory");                                                   \
    if (DO_A) {                                                                      \
      _Pragma("unroll") for (int i_=0;i_<4;i_++)                                     \
        _Pragma("unroll") for (int k_=0;k_<2;k_++)                                   \
          afr[i_][k_] = *(const bf8_t*)(smem + (SL)*32768 + (QM)*16384 + aoff[i_][k_]); \
    }                                                                                \
    if (DO_B) {                                                                      \
      _Pragma("unroll") for (int j_=0;j_<2;j_++)                                     \
        _Pragma("unroll") for (int k_=0;k_<2;k_++)                                   \
          bfr[QN][j_][k_] = *(const bf8_t*)(smem + (SL)*32768 + (QN)*16384 + boff[j_][k_]); \
    }                                                                                \
    asm volatile("s_waitcnt lgkmcnt(0)" ::: "memory");                               \
    __builtin_amdgcn_sched_barrier(0);                                               \
    __builtin_amdgcn_s_setprio(1);                                                   \
    _Pragma("unroll") for (int k_=0;k_<2;k_++)                                       \
      _Pragma("unroll") for (int i_=0;i_<4;i_++)                                     \
        _Pragma("unroll") for (int j_=0;j_<2;j_++)                                   \
          acc[QM][QN][i_][j_] = __builtin_amdgcn_mfma_f32_16x16x32_bf16(             \
              afr[i_][k_], bfr[QN][j_][k_], acc[QM][QN][i_][j_], 0,0,0);             \
    __builtin_amdgcn_s_setprio(0);                                                   \
    __builtin_amdgcn_s_barrier();                                                    \
  }

__global__ __launch_bounds__(512)
void gemm8p(const unsigned short* __restrict__ A,
            const unsigned short* __restrict__ B,
            unsigned short* __restrict__ C,
            int K, int N, long bStrideZ, long cStrideZ, int swz)
{
  extern __shared__ char smem[];   // [A: 2 slots x 2 halves x 16KB][B: same] = 128KB
  const int t = threadIdx.x;
  const int w = t>>6, l = t&63, q4 = l>>4, mr = l&15;
  const int wm = w>>2, wn = w&3;

  int ct, rt, zz;
  if (swz == 1) {
    const int id = (blockIdx.z*gridDim.y + blockIdx.y)*gridDim.x + blockIdx.x;
    const int xcd = id & 7, slot = id >> 3;
    zz = xcd; ct = slot % gridDim.x; rt = slot / gridDim.x;
  } else { ct = blockIdx.x; rt = blockIdx.y; zz = blockIdx.z; }

  const unsigned short* Ap = A + (size_t)rt*256*K;
  const unsigned short* Bp = B + (size_t)zz*bStrideZ + (size_t)ct*256*K;

  const unsigned short* aSrc[2];
  const unsigned short* bSrc[2];
  #pragma unroll
  for (int c=0;c<2;c++){
    const int o  = c*8192 + t*16;
    const int lb = o ^ (((o>>7)&7)<<4);
    const int row = lb>>7, kcol = (lb&127)>>1;
    aSrc[c] = Ap + (size_t)row*K + kcol;
    bSrc[c] = Bp + (size_t)row*K + kcol;
  }
  const size_t hK = (size_t)128*K;

  int aoff[4][2], boff[2][2];
  #pragma unroll
  for (int i=0;i<4;i++)
    #pragma unroll
    for (int kk=0;kk<2;kk++){
      const int row = wm*64 + i*16 + mr;
      int b_ = row*128 + kk*64 + q4*16;
      b_ ^= (row&7)<<4;
      aoff[i][kk] = b_;
    }
  #pragma unroll
  for (int j=0;j<2;j++)
    #pragma unroll
    for (int kk=0;kk<2;kk++){
      const int row = wn*32 + j*16 + mr;
      int b_ = row*128 + kk*64 + q4*16;
      b_ ^= (row&7)<<4;
      boff[j][kk] = 65536 + b_;
    }

  f32x4_t acc[2][2][4][2];
  #pragma unroll
  for (int a0=0;a0<2;a0++)
    #pragma unroll
    for (int a1=0;a1<2;a1++)
      #pragma unroll
      for (int a2=0;a2<4;a2++)
        #pragma unroll
        for (int a3=0;a3<2;a3++) acc[a0][a1][a2][a3] = (f32x4_t){0.f,0.f,0.f,0.f};

  bf8_t afr[4][2];
  bf8_t bfr[2][2][2];   // [QN][j][k] — both QN sets live across the 4 phases of an SL

  STG_A(0,0,0); STG_A(0,1,0); STG_B(0,0,0); STG_B(0,1,0);
  STG_A(1,0,1); STG_B(1,1,1);

  const int NITER = K >> 7;
  for (int it = 0; it < NITER-1; ++it){
    const int t1 = 2*it+1, t2 = 2*it+2, t3 = 2*it+3;
    PHASE(0,0,0, 1,1, STG_A(1,1,t1), VMW6);
    PHASE(0,0,1, 0,1, STG_B(1,0,t1), NOOP);
    PHASE(0,1,1, 1,0, STG_A(0,0,t2), NOOP);
    PHASE(0,1,0, 0,0, STG_B(0,1,t2), NOOP);
    PHASE(1,0,0, 1,1, STG_A(0,1,t2), VMW6);
    PHASE(1,0,1, 0,1, STG_B(0,0,t2), NOOP);
    PHASE(1,1,1, 1,0, STG_A(1,0,t3), NOOP);
    PHASE(1,1,0, 0,0, STG_B(1,1,t3), NOOP);
  }
  {
    const int t1 = 2*NITER-1;
    PHASE(0,0,0, 1,1, STG_A(1,1,t1), VMW6);
    PHASE(0,0,1, 0,1, STG_B(1,0,t1), NOOP);
    PHASE(0,1,1, 1,0, NOOP, NOOP);
    PHASE(0,1,0, 0,0, NOOP, NOOP);
    PHASE(1,0,0, 1,1, NOOP, VMW0);
    PHASE(1,0,1, 0,1, NOOP, NOOP);
    PHASE(1,1,1, 1,0, NOOP, NOOP);
    PHASE(1,1,0, 0,0, NOOP, NOOP);
  }

  unsigned short* Cp = C + (size_t)zz*cStrideZ;
  #pragma unroll
  for (int qm=0;qm<2;qm++)
    #pragma unroll
    for (int qn=0;qn<2;qn++)
      #pragma unroll
      for (int i=0;i<4;i++)
        #pragma unroll
        for (int j=0;j<2;j++){
          const long mb = (long)rt*256 + qm*128 + wm*64 + i*16 + q4*4;
          const long n  = (long)ct*256 + qn*128 + wn*32 + j*16 + mr;
          #pragma unroll
          for (int r=0;r<4;r++)
            Cp[(mb+r)*N + n] = f2bf(acc[qm][qn][i][j][r]);
        }
}

// ---------------- GEMM: C = A(MxK) * B(NxK)^T, 128x128 tile, 4 waves ----------------
template<int MODE>
__global__ __launch_bounds__(256)
void gemm_bt(const unsigned short* __restrict__ A,
             const unsigned short* __restrict__ Bbf,
             const float* __restrict__ Bf32,
             const float* __restrict__ bias,
             void* __restrict__ Cout,
             int K, int N,
             long bStrideZ, long cStrideZ,
             const int* __restrict__ sel,
             long selAStride, long selBStride, int selBiasStride,
             int swz)
{
  constexpr int BP = (MODE >= 2) ? 40 : 32;
  __shared__ unsigned short As[128*32];
  __shared__ unsigned short Bs[128*BP];

  int rt, ct, zz;
  if (swz == 1) {
    const int id = (blockIdx.z*gridDim.y + blockIdx.y)*gridDim.x + blockIdx.x;
    const int xcd = id & 7, slot = id >> 3;
    zz = xcd; ct = slot % gridDim.x; rt = slot / gridDim.x;
  } else if (swz == 2) {
    const int id = blockIdx.y*gridDim.x + blockIdx.x;
    const int xcd = id & 7, slot = id >> 3;
    rt = xcd*4 + (slot & 3); ct = slot >> 2; zz = 0;
  } else {
    rt = blockIdx.y; ct = blockIdx.x; zz = blockIdx.z;
  }

  const int t = threadIdx.x;
  const int w = t>>6, l = t&63, q4 = l>>4, mr = l&15;
  const int wm = (w&1)*64, wn = (w>>1)*64;
  const int sr = t>>2, cv = t&3;

  const unsigned short* Ap = A;
  const unsigned short* Bp = Bbf;
  const float* Bf_ = Bf32;
  const float* biasp = bias;
  if (MODE == 0) {
    Bp += (size_t)zz * bStrideZ;
  } else {
    const int ex = sel[rt>>2];
    if (MODE == 1) { Ap += (size_t)ex * selAStride; Bp += (size_t)ex * selBStride; }
    else           { Bf_ += (size_t)ex * selBStride; }
    biasp += (long)ex * selBiasStride;
  }

  f32x4_t acc[4][4];
  #pragma unroll
  for (int i=0;i<4;i++)
    #pragma unroll
    for (int j=0;j<4;j++) acc[i][j] = (f32x4_t){0.f,0.f,0.f,0.f};

  const unsigned short* gA = Ap + (size_t)(rt*128 + w*16 + (l>>2))*K + (l&3)*8;
  unsigned short* lA = As + w*512;
  const unsigned short* gB = nullptr;
  unsigned short* lB = Bs + w*512;
  if (MODE < 2) gB = Bp + (size_t)(ct*128 + w*16 + (l>>2))*K + (l&3)*8;

  for (int k0 = 0; k0 < K; k0 += 32) {
    uint4 b0, b1;
    if (MODE >= 2) {
      const float* Br0 = Bf_ + (long)(ct*128 + sr)*K + cv*8 + k0;
      const float* Br1 = Br0 + (long)64*K;
      float4 f0a = *(const float4*)Br0;  float4 f0b = *(const float4*)(Br0+4);
      float4 f1a = *(const float4*)Br1;  float4 f1b = *(const float4*)(Br1+4);
      union { unsigned short s[8]; uint4 v; } p0, p1;
      p0.s[0]=f2bf(f0a.x); p0.s[1]=f2bf(f0a.y); p0.s[2]=f2bf(f0a.z); p0.s[3]=f2bf(f0a.w);
      p0.s[4]=f2bf(f0b.x); p0.s[5]=f2bf(f0b.y); p0.s[6]=f2bf(f0b.z); p0.s[7]=f2bf(f0b.w);
      p1.s[0]=f2bf(f1a.x); p1.s[1]=f2bf(f1a.y); p1.s[2]=f2bf(f1a.z); p1.s[3]=f2bf(f1a.w);
      p1.s[4]=f2bf(f1b.x); p1.s[5]=f2bf(f1b.y); p1.s[6]=f2bf(f1b.z); p1.s[7]=f2bf(f1b.w);
      b0 = p0.v; b1 = p1.v;
    }
    __syncthreads();
    gl_lds16(gA + k0,                lA);
    gl_lds16(gA + (size_t)64*K + k0, lA + 2048);
    if (MODE < 2) {
      gl_lds16(gB + k0,                lB);
      gl_lds16(gB + (size_t)64*K + k0, lB + 2048);
    } else {
      *(uint4*)&Bs[sr*40 + cv*8]      = b0;
      *(uint4*)&Bs[(sr+64)*40 + cv*8] = b1;
    }
    __syncthreads();
    bf8_t af[4], bfv[4];
    #pragma unroll
    for (int i=0;i<4;i++) af[i]  = *(const bf8_t*)&As[(wm+i*16+mr)*32 + q4*8];
    #pragma unroll
    for (int j=0;j<4;j++) bfv[j] = *(const bf8_t*)&Bs[(wn+j*16+mr)*BP + q4*8];
    #pragma unroll
    for (int i=0;i<4;i++)
      #pragma unroll
      for (int j=0;j<4;j++)
        acc[i][j] = __builtin_amdgcn_mfma_f32_16x16x32_bf16(af[i], bfv[j], acc[i][j], 0,0,0);
  }

  const long Cld = N;
  unsigned short* Cb16 = (unsigned short*)Cout + (size_t)zz * cStrideZ;
  float* Cf32 = (float*)Cout;
  #pragma unroll
  for (int j=0;j<4;j++){
    const int n = ct*128 + wn + j*16 + mr;
    const float bv = (MODE==0) ? 0.f : biasp[n];
    #pragma unroll
    for (int i=0;i<4;i++){
      const long mbase = (long)rt*128 + wm + i*16 + q4*4;
      #pragma unroll
      for (int r=0;r<4;r++){
        const float v = acc[i][j][r] + bv;
        const long m = mbase + r;
        if (MODE==0 || MODE==1) {
          Cb16[m*Cld + n] = f2bf(v);
        } else if (MODE==2) {
          const float g = 0.5f*v*(1.0f + erff(v*0.70710678118654752f));
          Cb16[m*Cld + n] = f2bf(g);
        } else {
          Cf32[m*Cld + n] = v;
        }
      }
    }
  }
}

// ---------------- attention: 64 q-rows x (head, batch[, expert]) per WG, 32-key tiles --
// (R4-verified) LDS-op-minimized staging; K XOR-swizzled; V f16 tr-subtiled with
// ds_read_b64_tr_b16 (lane addr = base + 8*l); QK 16x16x32 bf16; PV 16x16x16 f16.
__global__ __launch_bounds__(256)
void attn_kernel(const unsigned short* __restrict__ qkv,
                 const int* __restrict__ mask,
                 unsigned short* __restrict__ ctx,
                 long qkvStrideZ, long ctxStrideZ, int swz)
{
  int qb, h, zz;
  if (swz) {
    const int id = (blockIdx.z*gridDim.y + blockIdx.y)*gridDim.x + blockIdx.x;
    const int xcd = id & 7, slot = id >> 3;
    const int sz = slot / 96, sxy = slot % 96;
    qb = sxy & 7; h = sxy >> 3; zz = xcd*8 + sz;
  } else { qb = blockIdx.x; h = blockIdx.y; zz = blockIdx.z; }
  const int b = zz & 7, e = zz >> 3;
  qkv += (size_t)e * qkvStrideZ;
  ctx += (size_t)e * ctxStrideZ;

  const int t = threadIdx.x, w = t>>6, l = t&63, q4 = l>>4, mr = l&15;
  __shared__ float maskf[512];
  __shared__ unsigned short Ks[32*64];
  __shared__ unsigned short Vt[2048];

  for (int i=t;i<512;i+=256) maskf[i] = mask[b*512 + i] ? 1.0f : 0.0f;

  const int srow = b*512 + qb*64 + w*16;
  const unsigned short* qp = qkv + (long)(srow+mr)*QKVN + h*192;
  const bf8_t qf0 = *(const bf8_t*)(qp + q4*8);
  const bf8_t qf1 = *(const bf8_t*)(qp + 32 + q4*8);

  f32x4_t cacc[4];
  #pragma unroll
  for (int d=0; d<4; d++) cacc[d] = (f32x4_t){0.f,0.f,0.f,0.f};
  float lsum = 0.f;

  const int skey = t>>3;
  const int sd   = (t&7)*8;
  const unsigned short* kgp = qkv + (long)(b*512 + skey)*QKVN + h*192 + 64 + sd;
  const unsigned short* vgp = kgp + 64;
  const long kstep = (long)32*QKVN;

  unsigned short* ksw = &Ks[skey*64 + (sd ^ ((skey&7)<<3))];
  unsigned short* vsw = &Vt[(skey>>4)*1024 + (sd>>4)*256 + ((skey>>2)&3)*64 + (skey&3)*16 + (sd&15)];

  const int kx  = (mr&7)<<3;
  const int k00i = mr*64      + ((q4*8)      ^ kx);
  const int k01i = mr*64      + ((32 + q4*8) ^ kx);
  const int k10i = (16+mr)*64 + ((q4*8)      ^ kx);
  const int k11i = (16+mr)*64 + ((32 + q4*8) ^ kx);

  const unsigned trb = (unsigned)(uintptr_t)(&Vt[0]) + (unsigned)(l*8);

  uint4 kreg = *(const uint4*)kgp;
  uint4 vreg = *(const uint4*)vgp;

  for (int kt=0; kt<16; kt++){
    __syncthreads();
    *(uint4*)ksw = kreg;
    {
      const unsigned short* pv = (const unsigned short*)&vreg;
      union { unsigned short s[8]; uint4 v; } hh;
      #pragma unroll
      for (int j=0;j<8;j++) hh.s[j] = __half_as_ushort(__float2half(bf2f(pv[j])));
      *(uint4*)vsw = hh.v;
    }
    if (kt < 15){
      kreg = *(const uint4*)(kgp + (long)(kt+1)*kstep);
      vreg = *(const uint4*)(vgp + (long)(kt+1)*kstep);
    }
    __syncthreads();

    const f32x4_t m0 = *(const f32x4_t*)&maskf[kt*32 + q4*4];
    const f32x4_t m1 = *(const f32x4_t*)&maskf[kt*32 + 16 + q4*4];
    const bf8_t k00 = *(const bf8_t*)&Ks[k00i];
    const bf8_t k01 = *(const bf8_t*)&Ks[k01i];
    const bf8_t k10 = *(const bf8_t*)&Ks[k10i];
    const bf8_t k11 = *(const bf8_t*)&Ks[k11i];
    f32x4_t st0 = (f32x4_t){0.f,0.f,0.f,0.f};
    f32x4_t st1 = (f32x4_t){0.f,0.f,0.f,0.f};
    st0 = __builtin_amdgcn_mfma_f32_16x16x32_bf16(k00, qf0, st0, 0,0,0);
    st0 = __builtin_amdgcn_mfma_f32_16x16x32_bf16(k01, qf1, st0, 0,0,0);
    st1 = __builtin_amdgcn_mfma_f32_16x16x32_bf16(k10, qf0, st1, 0,0,0);
    st1 = __builtin_amdgcn_mfma_f32_16x16x32_bf16(k11, qf1, st1, 0,0,0);

    f16x4_t vA0, vA1, vA2, vA3, vB0, vB1, vB2, vB3;
    asm volatile("ds_read_b64_tr_b16 %0, %1 offset:0"    : "=v"(vA0) : "v"(trb));
    asm volatile("ds_read_b64_tr_b16 %0, %1 offset:512"  : "=v"(vA1) : "v"(trb));
    asm volatile("ds_read_b64_tr_b16 %0, %1 offset:1024" : "=v"(vA2) : "v"(trb));
    asm volatile("ds_read_b64_tr_b16 %0, %1 offset:1536" : "=v"(vA3) : "v"(trb));
    asm volatile("ds_read_b64_tr_b16 %0, %1 offset:2048" : "=v"(vB0) : "v"(trb));
    asm volatile("ds_read_b64_tr_b16 %0, %1 offset:2560" : "=v"(vB1) : "v"(trb));
    asm volatile("ds_read_b64_tr_b16 %0, %1 offset:3072" : "=v"(vB2) : "v"(trb));
    asm volatile("ds_read_b64_tr_b16 %0, %1 offset:3584" : "=v"(vB3) : "v"(trb));

    f16x4_t pf0, pf1;
    #pragma unroll
    for (int r=0;r<4;r++){
      const float p = __builtin_exp2f(st0[r]*SC2_) * m0[r];
      lsum += p;
      pf0[r] = (_Float16)p;
    }
    #pragma unroll
    for (int r=0;r<4;r++){
      const float p = __builtin_exp2f(st1[r]*SC2_) * m1[r];
      lsum += p;
      pf1[r] = (_Float16)p;
    }

    asm volatile("s_waitcnt lgkmcnt(0)" ::: "memory");
    __builtin_amdgcn_sched_barrier(0);

    cacc[0] = __builtin_amdgcn_mfma_f32_16x16x16f16(pf0, vA0, cacc[0], 0,0,0);
    cacc[1] = __builtin_amdgcn_mfma_f32_16x16x16f16(pf0, vA1, cacc[1], 0,0,0);
    cacc[2] = __builtin_amdgcn_mfma_f32_16x16x16f16(pf0, vA2, cacc[2], 0,0,0);
    cacc[3] = __builtin_amdgcn_mfma_f32_16x16x16f16(pf0, vA3, cacc[3], 0,0,0);
    cacc[0] = __builtin_amdgcn_mfma_f32_16x16x16f16(pf1, vB0, cacc[0], 0,0,0);
    cacc[1] = __builtin_amdgcn_mfma_f32_16x16x16f16(pf1, vB1, cacc[1], 0,0,0);
    cacc[2] = __builtin_amdgcn_mfma_f32_16x16x16f16(pf1, vB2, cacc[2], 0,0,0);
    cacc[3] = __builtin_amdgcn_mfma_f32_16x16x16f16(pf1, vB3, cacc[3], 0,0,0);
  }

  lsum += __shfl_xor(lsum, 16);
  lsum += __shfl_xor(lsum, 32);
  #pragma unroll
  for (int r=0;r<4;r++){
    const int m2 = q4*4 + r;
    const float lr = __shfl(lsum, m2);
    const float inv = 1.0f/lr;
    const long orow = (long)(b*512 + qb*64 + w*16 + m2)*Dd + h*64;
    #pragma unroll
    for (int dblk=0; dblk<4; dblk++){
      ctx[orow + dblk*16 + mr] = f2bf(cacc[dblk][r]*inv);
    }
  }
}

// ---------------- ctxmean: mean over seq of ctx -> (e,b,d) fp32 ----------------
__global__ void ctxmean_kernel(const unsigned short* __restrict__ ctx, float* __restrict__ out){
  const int d = blockIdx.x*256 + threadIdx.x;
  const int b = blockIdx.y, e = blockIdx.z;
  const unsigned short* p = ctx + ((size_t)e*MROWS + b*512)*Dd + d;
  float s = 0.f;
  for (int i=0;i<512;i++) s += bf2f(p[(size_t)i*Dd]);
  out[((size_t)e*Bb + b)*Dd + d] = s * (1.0f/512.0f);
}

// ---------------- featgemm ----------------
__global__ __launch_bounds__(256)
void featgemm_kernel(const float* __restrict__ ctxmean, const unsigned short* __restrict__ Wdb,
                     const float* __restrict__ bd, float* __restrict__ feat){
  __shared__ float xs[Dd];
  const int b = blockIdx.x, e = blockIdx.y;
  const int t = threadIdx.x;
  for (int i=t;i<Dd;i+=256) xs[i] = ctxmean[((size_t)e*Bb+b)*Dd + i];
  __syncthreads();
  #pragma unroll
  for (int c0=0;c0<3;c0++){
    const int col = c0*256 + t;
    const unsigned short* wr = Wdb + ((size_t)e*Dd + col)*Dd;
    float s = 0.f;
    for (int k=0;k<Dd;k+=8){
      bf8_t wv = *(const bf8_t*)(wr + k);
      const unsigned short* wp = (const unsigned short*)&wv;
      #pragma unroll
      for (int j=0;j<8;j++) s += bf2f(wp[j]) * xs[k+j];
    }
    feat[((size_t)e*Bb+b)*Dd + col] = s + bd[(size_t)e*Dd + col];
  }
}

// ---------------- routing ----------------
__global__ void routing_kernel(const float* __restrict__ feat, const float* __restrict__ centers,
                               int* __restrict__ sel)
{
  __shared__ float d2s[64];
  const int t = threadIdx.x;
  if (t < 64){
    const int e = t>>3, b = t&7;
    const float* f = feat + (long)(e*Bb + b)*Dd;
    const float* c = centers + (long)e*Dd;
    float s = 0.f;
    for (int d=0; d<Dd; d++){
      const float df = f[d] - c[d];
      s += df*df;
    }
    d2s[t] = s;
  }
  __syncthreads();
  if (t < 8){
    float best = 3.4e38f; int bi = 0;
    for (int e=0;e<8;e++){ const float v = d2s[e*8+t]; if (v < best){ best=v; bi=e; } }
    sel[t] = bi;
  }
}

// ---------------- h = LN1(attsel+x) ----------------
__global__ __launch_bounds__(256)
void hprep_kernel(const unsigned short* __restrict__ attsel, const float* __restrict__ x,
                  const float* __restrict__ g, const float* __restrict__ be,
                  const int* __restrict__ sel, unsigned short* __restrict__ hbuf)
{
  const int w = threadIdx.x>>6, l = threadIdx.x&63;
  const int row = blockIdx.x*4 + w;
  const int b = row>>9;
  const int e = sel[b];
  const unsigned short* ap = attsel + (long)row*Dd;
  const float* xp = x + (long)row*Dd;
  float v[12]; float s = 0.f;
  #pragma unroll
  for (int i=0;i<12;i++){ const int d = i*64 + l; v[i] = bf2f(ap[d]) + xp[d]; s += v[i]; }
  #pragma unroll
  for (int o=32;o>0;o>>=1) s += __shfl_xor(s, o);
  const float mean = s * (1.0f/768.0f);
  float vs = 0.f;
  #pragma unroll
  for (int i=0;i<12;i++){ const float dd = v[i]-mean; vs += dd*dd; }
  #pragma unroll
  for (int o=32;o>0;o>>=1) vs += __shfl_xor(vs, o);
  const float rs = rsqrtf(vs*(1.0f/768.0f) + 1e-12f);
  #pragma unroll
  for (int i=0;i<12;i++){
    const int d = i*64 + l;
    hbuf[(long)row*Dd + d] = f2bf((v[i]-mean)*rs*g[(long)e*Dd+d] + be[(long)e*Dd+d]);
  }
}

// ---------------- out = LN2(h + ffn) ----------------
__global__ __launch_bounds__(256)
void ln2_kernel(const unsigned short* __restrict__ hbuf, const float* __restrict__ tbuf,
                const float* __restrict__ g, const float* __restrict__ be,
                const int* __restrict__ sel, float* __restrict__ out)
{
  const int w = threadIdx.x>>6, l = threadIdx.x&63;
  const int row = blockIdx.x*4 + w;
  const int b = row>>9;
  const int e = sel[b];
  const unsigned short* hp = hbuf + (long)row*Dd;
  const float* tp = tbuf + (long)row*Dd;
  float v[12]; float s = 0.f;
  #pragma unroll
  for (int i=0;i<12;i++){ const int d = i*64 + l; v[i] = bf2f(hp[d]) + tp[d]; s += v[i]; }
  #pragma unroll
  for (int o=32;o>0;o>>=1) s += __shfl_xor(s, o);
  const float mean = s * (1.0f/768.0f);
  float vs = 0.f;
  #pragma unroll
  for (int i=0;i<12;i++){ const float dd = v[i]-mean; vs += dd*dd; }
  #pragma unroll
  for (int o=32;o>0;o>>=1) vs += __shfl_xor(vs, o);
  const float rs = rsqrtf(vs*(1.0f/768.0f) + 1e-12f);
  #pragma unroll
  for (int i=0;i<12;i++){
    const int d = i*64 + l;
    out[(long)row*Dd + d] = (v[i]-mean)*rs*g[(long)e*Dd+d] + be[(long)e*Dd+d];
  }
}

// ---------------- launch ----------------
extern "C" void kernel_launch(void* const* d_in, const int* in_sizes, int n_in,
                              void* d_out, int out_size, void* d_ws, size_t ws_size,
                              hipStream_t stream)
{
  const float* x      = (const float*)d_in[0];
  const int*   mask   = (const int*)d_in[1];
  const float* Wqkv   = (const float*)d_in[2];
  const float* Wd     = (const float*)d_in[3];
  const float* bd     = (const float*)d_in[4];
  const float* ln1g   = (const float*)d_in[5];
  const float* ln1b   = (const float*)d_in[6];
  const float* W1     = (const float*)d_in[7];
  const float* b1     = (const float*)d_in[8];
  const float* W2     = (const float*)d_in[9];
  const float* b2     = (const float*)d_in[10];
  const float* ln2g   = (const float*)d_in[11];
  const float* ln2b   = (const float*)d_in[12];
  const float* centers= (const float*)d_in[13];

  hipFuncSetAttribute((const void*)gemm8p, hipFuncAttributeMaxDynamicSharedMemorySize, 131072);

  int zc;
  if      (ws_size >= 258347264ull) zc = 8;
  else if (ws_size >= 182849792ull) zc = 4;
  else if (ws_size >= 145101056ull) zc = 2;
  else                              zc = 1;

  char* p = (char*)d_ws;
  auto carve = [&](size_t bytes)->char*{ char* r = p; p += ((bytes + 255) & ~(size_t)255); return r; };

  unsigned short* xb      = (unsigned short*)carve((size_t)MROWS*Dd*2);
  unsigned short* Wqkvb   = (unsigned short*)carve((size_t)Ee*QKVN*Dd*2);
  unsigned short* Wdb     = (unsigned short*)carve((size_t)Ee*Dd*Dd*2);
  float*          ctxmean = (float*)carve((size_t)Ee*Bb*Dd*4);
  float*          feat    = (float*)carve((size_t)Ee*Bb*Dd*4);
  int*            sel     = (int*)carve(256);
  unsigned short* hbuf    = (unsigned short*)carve((size_t)MROWS*Dd*2);
  unsigned short* attsel  = (unsigned short*)carve((size_t)MROWS*Dd*2);
  unsigned short* qkvchk  = (unsigned short*)carve((size_t)zc*MROWS*QKVN*2);
  unsigned short* ctx_all = (unsigned short*)carve((size_t)Ee*MROWS*Dd*2);
  unsigned short* Gbuf = attsel;
  float*          tbuf = (float*)ctx_all;

  cast_kernel<<<(MROWS*Dd/4 + 255)/256, 256, 0, stream>>>(x, xb, MROWS*Dd);
  cast_kernel<<<(Ee*QKVN*Dd/4 + 255)/256, 256, 0, stream>>>(Wqkv, Wqkvb, Ee*QKVN*Dd);
  cast_kernel<<<(Ee*Dd*Dd/4 + 255)/256, 256, 0, stream>>>(Wd, Wdb, Ee*Dd*Dd);

  const int nchunk = Ee / zc;
  for (int c = 0; c < nchunk; c++){
    gemm8p<<<dim3(QKVN/256, MROWS/256, zc), 512, 131072, stream>>>(
        xb, Wqkvb + (size_t)c*zc*QKVN*Dd, qkvchk,
        Dd, QKVN, (long)QKVN*Dd, (long)MROWS*QKVN, (zc==8) ? 1 : 0);
    attn_kernel<<<dim3(8, Hh, Bb*zc), 256, 0, stream>>>(
        qkvchk, mask, ctx_all + (size_t)c*zc*MROWS*Dd,
        (long)MROWS*QKVN, (long)MROWS*Dd, (zc==8) ? 1 : 0);
    ctxmean_kernel<<<dim3(3, Bb, zc), 256, 0, stream>>>(
        ctx_all + (size_t)c*zc*MROWS*Dd, ctxmean + (size_t)c*zc*Bb*Dd);
  }

  featgemm_kernel<<<dim3(Bb, Ee), 256, 0, stream>>>(ctxmean, Wdb, bd, feat);
  routing_kernel<<<1, 64, 0, stream>>>(feat, centers, sel);

  gemm_bt<1><<<dim3(Dd/128, MROWS/128, 1), 256, 0, stream>>>(
      ctx_all, Wdb, nullptr, bd, attsel, Dd, Dd, 0, 0,
      sel, (long)MROWS*Dd, (long)Dd*Dd, Dd, 2);

  hprep_kernel<<<MROWS/4, 256, 0, stream>>>(attsel, x, ln1g, ln1b, sel, hbuf);
  gemm_bt<2><<<dim3(DFF/128, MROWS/128, 1), 256, 0, stream>>>(
      hbuf, nullptr, W1, b1, Gbuf, Dd, DFF, 0, 0,
      sel, 0, (long)DFF*Dd, DFF, 2);
  gemm_bt<3><<<dim3(Dd/128, MROWS/128, 1), 256, 0, stream>>>(
      Gbuf, nullptr, W2, b2, tbuf, DFF, Dd, 0, 0,
      sel, 0, (long)Dd*DFF, Dd, 2);
  ln2_kernel<<<MROWS/4, 256, 0, stream>>>(hbuf, tbuf, ln2g, ln2b, sel, (float*)d_out);
}

// Round 7
// 730.889 us; speedup vs baseline: 1.0909x; 1.0909x over previous
//
#include <hip/hip_runtime.h>
#include <hip/hip_fp16.h>
#include <math.h>
#include <stdint.h>

#define Bb 8
#define Ss 512
#define Dd 768
#define Hh 12
#define Ee 8
#define DFF 3072
#define MROWS 4096          // B*S
#define QKVN 2304           // H*3*DH

static __device__ const float SCALE_ = 0.036084391824351615f; // 768^-0.5
static __device__ const float SC2_   = 0.05206262648008056f;  // 768^-0.5 * log2(e)

typedef short bf8_t __attribute__((ext_vector_type(8)));
typedef _Float16 f16x4_t __attribute__((ext_vector_type(4)));
typedef float f32x4_t __attribute__((ext_vector_type(4)));

__device__ __forceinline__ float bf2f(unsigned short u){
  union { unsigned int i; float f; } x; x.i = ((unsigned int)u)<<16; return x.f;
}
__device__ __forceinline__ unsigned short f2bf(float f){
  union { float f; unsigned int i; } x; x.f = f;
  unsigned int u = x.i;
  return (unsigned short)((u + 0x7fffu + ((u>>16)&1u)) >> 16);
}

// async global->LDS, 16B per lane; LDS dest is wave-uniform base + lane*16
__device__ __forceinline__ void gl_lds16(const void* g, void* l){
  __builtin_amdgcn_global_load_lds(
      (const __attribute__((address_space(1))) unsigned int*)(g),
      (__attribute__((address_space(3))) unsigned int*)(uintptr_t)(l),
      16, 0, 0);
}

// ---------------- cast fp32 -> bf16 (n % 4 == 0) ----------------
__global__ void cast_kernel(const float* __restrict__ in, unsigned short* __restrict__ out, int n){
  int i = (blockIdx.x*256 + threadIdx.x)*4;
  if (i >= n) return;
  const float4 v = *(const float4*)(in + i);
  ushort4 o; o.x=f2bf(v.x); o.y=f2bf(v.y); o.z=f2bf(v.z); o.w=f2bf(v.w);
  *(ushort4*)(out + i) = o;
}

// ---------------- cast fp32 -> bf16, per-expert, skipped if expert unused ----------------
__global__ void castsel_kernel(const float* __restrict__ in, unsigned short* __restrict__ out,
                               int perExpert, const int* __restrict__ sel){
  const int e = blockIdx.z;
  bool used = false;
  #pragma unroll
  for (int b=0;b<8;b++) used |= (sel[b] == e);
  if (!used) return;
  const long i = ((long)blockIdx.x*256 + threadIdx.x)*4;
  if (i >= perExpert) return;
  const float4 v = *(const float4*)(in + (long)e*perExpert + i);
  ushort4 o; o.x=f2bf(v.x); o.y=f2bf(v.y); o.z=f2bf(v.z); o.w=f2bf(v.w);
  *(ushort4*)(out + (long)e*perExpert + i) = o;
}

// =====================================================================================
// 256x256 tile, 8-wave, 8-phase pipelined bf16 GEMM: C = A(MxK) * B(NxK)^T  (QKV)
// R4-proven configuration (141 us, MfmaUtil 35, no spills). R5/R6's B-register cache
// reverted: compiler pins 128 VGPR regardless of launch bounds -> in-loop spills.
// =====================================================================================
#define VMW6 asm volatile("s_waitcnt vmcnt(6)" ::: "memory")
#define VMW0 asm volatile("s_waitcnt vmcnt(0)" ::: "memory")
#define NOOP ((void)0)

#define STG_A(SL,H,KT) { char* d_ = smem + (SL)*32768 + (H)*16384 + w*1024;          \
    gl_lds16(aSrc[0] + (size_t)(H)*hK + (size_t)(KT)*64, d_);                        \
    gl_lds16(aSrc[1] + (size_t)(H)*hK + (size_t)(KT)*64, d_ + 8192); }
#define STG_B(SL,H,KT) { char* d_ = smem + 65536 + (SL)*32768 + (H)*16384 + w*1024;  \
    gl_lds16(bSrc[0] + (size_t)(H)*hK + (size_t)(KT)*64, d_);                        \
    gl_lds16(bSrc[1] + (size_t)(H)*hK + (size_t)(KT)*64, d_ + 8192); }

#define PHASE(SL, QM, QN, DO_A, STAGE, WAITC)                                        \
  {                                                                                  \
    STAGE;                                                                           \
    WAITC;                                                                           \
    __builtin_amdgcn_s_barrier();                                                    \
    asm volatile("" ::: "memory");                                                   \
    if (DO_A) {                                                                      \
      _Pragma("unroll") for (int i_=0;i_<4;i_++)                                     \
        _Pragma("unroll") for (int k_=0;k_<2;k_++)                                   \
          afr[i_][k_] = *(const bf8_t*)(smem + (SL)*32768 + (QM)*16384 + aoff[i_][k_]); \
    }                                                                                \
    _Pragma("unroll") for (int j_=0;j_<2;j_++)                                       \
      _Pragma("unroll") for (int k_=0;k_<2;k_++)                                     \
        bfr[j_][k_] = *(const bf8_t*)(smem + (SL)*32768 + (QN)*16384 + boff[j_][k_]); \
    asm volatile("s_waitcnt lgkmcnt(0)" ::: "memory");                               \
    __builtin_amdgcn_sched_barrier(0);                                               \
    __builtin_amdgcn_s_setprio(1);                                                   \
    _Pragma("unroll") for (int k_=0;k_<2;k_++)                                       \
      _Pragma("unroll") for (int i_=0;i_<4;i_++)                                     \
        _Pragma("unroll") for (int j_=0;j_<2;j_++)                                   \
          acc[QM][QN][i_][j_] = __builtin_amdgcn_mfma_f32_16x16x32_bf16(             \
              afr[i_][k_], bfr[j_][k_], acc[QM][QN][i_][j_], 0,0,0);                 \
    __builtin_amdgcn_s_setprio(0);                                                   \
    __builtin_amdgcn_s_barrier();                                                    \
  }

__global__ __launch_bounds__(512, 2)
void gemm8p(const unsigned short* __restrict__ A,
            const unsigned short* __restrict__ B,
            unsigned short* __restrict__ C,
            int K, int N, long bStrideZ, long cStrideZ, int swz)
{
  extern __shared__ char smem[];   // [A: 2 slots x 2 halves x 16KB][B: same] = 128KB
  const int t = threadIdx.x;
  const int w = t>>6, l = t&63, q4 = l>>4, mr = l&15;
  const int wm = w>>2, wn = w&3;

  int ct, rt, zz;
  if (swz == 1) {
    const int id = (blockIdx.z*gridDim.y + blockIdx.y)*gridDim.x + blockIdx.x;
    const int xcd = id & 7, slot = id >> 3;
    zz = xcd; ct = slot % gridDim.x; rt = slot / gridDim.x;
  } else { ct = blockIdx.x; rt = blockIdx.y; zz = blockIdx.z; }

  const unsigned short* Ap = A + (size_t)rt*256*K;
  const unsigned short* Bp = B + (size_t)zz*bStrideZ + (size_t)ct*256*K;

  const unsigned short* aSrc[2];
  const unsigned short* bSrc[2];
  #pragma unroll
  for (int c=0;c<2;c++){
    const int o  = c*8192 + t*16;
    const int lb = o ^ (((o>>7)&7)<<4);
    const int row = lb>>7, kcol = (lb&127)>>1;
    aSrc[c] = Ap + (size_t)row*K + kcol;
    bSrc[c] = Bp + (size_t)row*K + kcol;
  }
  const size_t hK = (size_t)128*K;

  int aoff[4][2], boff[2][2];
  #pragma unroll
  for (int i=0;i<4;i++)
    #pragma unroll
    for (int kk=0;kk<2;kk++){
      const int row = wm*64 + i*16 + mr;
      int b_ = row*128 + kk*64 + q4*16;
      b_ ^= (row&7)<<4;
      aoff[i][kk] = b_;
    }
  #pragma unroll
  for (int j=0;j<2;j++)
    #pragma unroll
    for (int kk=0;kk<2;kk++){
      const int row = wn*32 + j*16 + mr;
      int b_ = row*128 + kk*64 + q4*16;
      b_ ^= (row&7)<<4;
      boff[j][kk] = 65536 + b_;
    }

  f32x4_t acc[2][2][4][2];
  #pragma unroll
  for (int a0=0;a0<2;a0++)
    #pragma unroll
    for (int a1=0;a1<2;a1++)
      #pragma unroll
      for (int a2=0;a2<4;a2++)
        #pragma unroll
        for (int a3=0;a3<2;a3++) acc[a0][a1][a2][a3] = (f32x4_t){0.f,0.f,0.f,0.f};

  bf8_t afr[4][2], bfr[2][2];

  STG_A(0,0,0); STG_A(0,1,0); STG_B(0,0,0); STG_B(0,1,0);
  STG_A(1,0,1); STG_B(1,1,1);

  const int NITER = K >> 7;
  for (int it = 0; it < NITER-1; ++it){
    const int t1 = 2*it+1, t2 = 2*it+2, t3 = 2*it+3;
    PHASE(0,0,0, 1, STG_A(1,1,t1), VMW6);
    PHASE(0,0,1, 0, STG_B(1,0,t1), NOOP);
    PHASE(0,1,1, 1, STG_A(0,0,t2), NOOP);
    PHASE(0,1,0, 0, STG_B(0,1,t2), NOOP);
    PHASE(1,0,0, 1, STG_A(0,1,t2), VMW6);
    PHASE(1,0,1, 0, STG_B(0,0,t2), NOOP);
    PHASE(1,1,1, 1, STG_A(1,0,t3), NOOP);
    PHASE(1,1,0, 0, STG_B(1,1,t3), NOOP);
  }
  {
    const int t1 = 2*NITER-1;
    PHASE(0,0,0, 1, STG_A(1,1,t1), VMW6);
    PHASE(0,0,1, 0, STG_B(1,0,t1), NOOP);
    PHASE(0,1,1, 1, NOOP, NOOP);
    PHASE(0,1,0, 0, NOOP, NOOP);
    PHASE(1,0,0, 1, NOOP, VMW0);
    PHASE(1,0,1, 0, NOOP, NOOP);
    PHASE(1,1,1, 1, NOOP, NOOP);
    PHASE(1,1,0, 0, NOOP, NOOP);
  }

  unsigned short* Cp = C + (size_t)zz*cStrideZ;
  #pragma unroll
  for (int qm=0;qm<2;qm++)
    #pragma unroll
    for (int qn=0;qn<2;qn++)
      #pragma unroll
      for (int i=0;i<4;i++)
        #pragma unroll
        for (int j=0;j<2;j++){
          const long mb = (long)rt*256 + qm*128 + wm*64 + i*16 + q4*4;
          const long n  = (long)ct*256 + qn*128 + wn*32 + j*16 + mr;
          #pragma unroll
          for (int r=0;r<4;r++)
            Cp[(mb+r)*N + n] = f2bf(acc[qm][qn][i][j][r]);
        }
}

// ---------------- GEMM: C = A(MxK) * B(NxK)^T, 128x128 tile, 4 waves ----------------
// MODE 1: A+B bf16 (sel-idx strides), bias,        store bf16   (dense attn out)
// MODE 2: B fp32 (sel-idx), bias, GELU,            store bf16   (FFN1 fallback)
// MODE 3: B fp32 (sel-idx), bias,                  store fp32   (FFN2 fallback)
// MODE 4: A+B bf16 (sel-idx, A stride 0), bias, GELU, store bf16 (FFN1 fast path)
// MODE 5: A+B bf16 (sel-idx, A stride 0), bias,    store fp32   (FFN2 fast path)
template<int MODE>
__global__ __launch_bounds__(256)
void gemm_bt(const unsigned short* __restrict__ A,
             const unsigned short* __restrict__ Bbf,
             const float* __restrict__ Bf32,
             const float* __restrict__ bias,
             void* __restrict__ Cout,
             int K, int N,
             long bStrideZ, long cStrideZ,
             const int* __restrict__ sel,
             long selAStride, long selBStride, int selBiasStride,
             int swz)
{
  constexpr bool BF16B = (MODE <= 1 || MODE >= 4);
  constexpr int BP = BF16B ? 32 : 40;
  __shared__ unsigned short As[128*32];
  __shared__ unsigned short Bs[128*BP];

  int rt, ct, zz;
  if (swz == 1) {
    const int id = (blockIdx.z*gridDim.y + blockIdx.y)*gridDim.x + blockIdx.x;
    const int xcd = id & 7, slot = id >> 3;
    zz = xcd; ct = slot % gridDim.x; rt = slot / gridDim.x;
  } else if (swz == 2) {
    const int id = blockIdx.y*gridDim.x + blockIdx.x;
    const int xcd = id & 7, slot = id >> 3;
    rt = xcd*4 + (slot & 3); ct = slot >> 2; zz = 0;
  } else {
    rt = blockIdx.y; ct = blockIdx.x; zz = blockIdx.z;
  }

  const int t = threadIdx.x;
  const int w = t>>6, l = t&63, q4 = l>>4, mr = l&15;
  const int wm = (w&1)*64, wn = (w>>1)*64;
  const int sr = t>>2, cv = t&3;

  const unsigned short* Ap = A;
  const unsigned short* Bp = Bbf;
  const float* Bf_ = Bf32;
  const float* biasp = bias;
  if (MODE == 0) {
    Bp += (size_t)zz * bStrideZ;
  } else {
    const int ex = sel[rt>>2];
    if (MODE == 1 || MODE >= 4) { Ap += (size_t)ex * selAStride; Bp += (size_t)ex * selBStride; }
    else                        { Bf_ += (size_t)ex * selBStride; }
    biasp += (long)ex * selBiasStride;
  }

  f32x4_t acc[4][4];
  #pragma unroll
  for (int i=0;i<4;i++)
    #pragma unroll
    for (int j=0;j<4;j++) acc[i][j] = (f32x4_t){0.f,0.f,0.f,0.f};

  const unsigned short* gA = Ap + (size_t)(rt*128 + w*16 + (l>>2))*K + (l&3)*8;
  unsigned short* lA = As + w*512;
  const unsigned short* gB = nullptr;
  unsigned short* lB = Bs + w*512;
  if (BF16B) gB = Bp + (size_t)(ct*128 + w*16 + (l>>2))*K + (l&3)*8;

  for (int k0 = 0; k0 < K; k0 += 32) {
    uint4 b0, b1;
    if (!BF16B) {
      const float* Br0 = Bf_ + (long)(ct*128 + sr)*K + cv*8 + k0;
      const float* Br1 = Br0 + (long)64*K;
      float4 f0a = *(const float4*)Br0;  float4 f0b = *(const float4*)(Br0+4);
      float4 f1a = *(const float4*)Br1;  float4 f1b = *(const float4*)(Br1+4);
      union { unsigned short s[8]; uint4 v; } p0, p1;
      p0.s[0]=f2bf(f0a.x); p0.s[1]=f2bf(f0a.y); p0.s[2]=f2bf(f0a.z); p0.s[3]=f2bf(f0a.w);
      p0.s[4]=f2bf(f0b.x); p0.s[5]=f2bf(f0b.y); p0.s[6]=f2bf(f0b.z); p0.s[7]=f2bf(f0b.w);
      p1.s[0]=f2bf(f1a.x); p1.s[1]=f2bf(f1a.y); p1.s[2]=f2bf(f1a.z); p1.s[3]=f2bf(f1a.w);
      p1.s[4]=f2bf(f1b.x); p1.s[5]=f2bf(f1b.y); p1.s[6]=f2bf(f1b.z); p1.s[7]=f2bf(f1b.w);
      b0 = p0.v; b1 = p1.v;
    }
    __syncthreads();
    gl_lds16(gA + k0,                lA);
    gl_lds16(gA + (size_t)64*K + k0, lA + 2048);
    if (BF16B) {
      gl_lds16(gB + k0,                lB);
      gl_lds16(gB + (size_t)64*K + k0, lB + 2048);
    } else {
      *(uint4*)&Bs[sr*40 + cv*8]      = b0;
      *(uint4*)&Bs[(sr+64)*40 + cv*8] = b1;
    }
    __syncthreads();
    bf8_t af[4], bfv[4];
    #pragma unroll
    for (int i=0;i<4;i++) af[i]  = *(const bf8_t*)&As[(wm+i*16+mr)*32 + q4*8];
    #pragma unroll
    for (int j=0;j<4;j++) bfv[j] = *(const bf8_t*)&Bs[(wn+j*16+mr)*BP + q4*8];
    #pragma unroll
    for (int i=0;i<4;i++)
      #pragma unroll
      for (int j=0;j<4;j++)
        acc[i][j] = __builtin_amdgcn_mfma_f32_16x16x32_bf16(af[i], bfv[j], acc[i][j], 0,0,0);
  }

  const long Cld = N;
  unsigned short* Cb16 = (unsigned short*)Cout + (size_t)zz * cStrideZ;
  float* Cf32 = (float*)Cout;
  #pragma unroll
  for (int j=0;j<4;j++){
    const int n = ct*128 + wn + j*16 + mr;
    const float bv = (MODE==0) ? 0.f : biasp[n];
    #pragma unroll
    for (int i=0;i<4;i++){
      const long mbase = (long)rt*128 + wm + i*16 + q4*4;
      #pragma unroll
      for (int r=0;r<4;r++){
        const float v = acc[i][j][r] + bv;
        const long m = mbase + r;
        if (MODE==0 || MODE==1) {
          Cb16[m*Cld + n] = f2bf(v);
        } else if (MODE==2 || MODE==4) {
          const float g = 0.5f*v*(1.0f + erff(v*0.70710678118654752f));
          Cb16[m*Cld + n] = f2bf(g);
        } else {
          Cf32[m*Cld + n] = v;
        }
      }
    }
  }
}

// ---------------- attention: 64 q-rows x (head, batch[, expert]) per WG, 32-key tiles --
// (R4-verified) LDS-op-minimized staging; K XOR-swizzled; V f16 tr-subtiled with
// ds_read_b64_tr_b16 (lane addr = base + 8*l); QK 16x16x32 bf16; PV 16x16x16 f16.
__global__ __launch_bounds__(256)
void attn_kernel(const unsigned short* __restrict__ qkv,
                 const int* __restrict__ mask,
                 unsigned short* __restrict__ ctx,
                 long qkvStrideZ, long ctxStrideZ, int swz)
{
  int qb, h, zz;
  if (swz) {
    const int id = (blockIdx.z*gridDim.y + blockIdx.y)*gridDim.x + blockIdx.x;
    const int xcd = id & 7, slot = id >> 3;
    const int sz = slot / 96, sxy = slot % 96;
    qb = sxy & 7; h = sxy >> 3; zz = xcd*8 + sz;
  } else { qb = blockIdx.x; h = blockIdx.y; zz = blockIdx.z; }
  const int b = zz & 7, e = zz >> 3;
  qkv += (size_t)e * qkvStrideZ;
  ctx += (size_t)e * ctxStrideZ;

  const int t = threadIdx.x, w = t>>6, l = t&63, q4 = l>>4, mr = l&15;
  __shared__ float maskf[512];
  __shared__ unsigned short Ks[32*64];
  __shared__ unsigned short Vt[2048];

  for (int i=t;i<512;i+=256) maskf[i] = mask[b*512 + i] ? 1.0f : 0.0f;

  const int srow = b*512 + qb*64 + w*16;
  const unsigned short* qp = qkv + (long)(srow+mr)*QKVN + h*192;
  const bf8_t qf0 = *(const bf8_t*)(qp + q4*8);
  const bf8_t qf1 = *(const bf8_t*)(qp + 32 + q4*8);

  f32x4_t cacc[4];
  #pragma unroll
  for (int d=0; d<4; d++) cacc[d] = (f32x4_t){0.f,0.f,0.f,0.f};
  float lsum = 0.f;

  const int skey = t>>3;
  const int sd   = (t&7)*8;
  const unsigned short* kgp = qkv + (long)(b*512 + skey)*QKVN + h*192 + 64 + sd;
  const unsigned short* vgp = kgp + 64;
  const long kstep = (long)32*QKVN;

  unsigned short* ksw = &Ks[skey*64 + (sd ^ ((skey&7)<<3))];
  unsigned short* vsw = &Vt[(skey>>4)*1024 + (sd>>4)*256 + ((skey>>2)&3)*64 + (skey&3)*16 + (sd&15)];

  const int kx  = (mr&7)<<3;
  const int k00i = mr*64      + ((q4*8)      ^ kx);
  const int k01i = mr*64      + ((32 + q4*8) ^ kx);
  const int k10i = (16+mr)*64 + ((q4*8)      ^ kx);
  const int k11i = (16+mr)*64 + ((32 + q4*8) ^ kx);

  const unsigned trb = (unsigned)(uintptr_t)(&Vt[0]) + (unsigned)(l*8);

  uint4 kreg = *(const uint4*)kgp;
  uint4 vreg = *(const uint4*)vgp;

  for (int kt=0; kt<16; kt++){
    __syncthreads();
    *(uint4*)ksw = kreg;
    {
      const unsigned short* pv = (const unsigned short*)&vreg;
      union { unsigned short s[8]; uint4 v; } hh;
      #pragma unroll
      for (int j=0;j<8;j++) hh.s[j] = __half_as_ushort(__float2half(bf2f(pv[j])));
      *(uint4*)vsw = hh.v;
    }
    if (kt < 15){
      kreg = *(const uint4*)(kgp + (long)(kt+1)*kstep);
      vreg = *(const uint4*)(vgp + (long)(kt+1)*kstep);
    }
    __syncthreads();

    const f32x4_t m0 = *(const f32x4_t*)&maskf[kt*32 + q4*4];
    const f32x4_t m1 = *(const f32x4_t*)&maskf[kt*32 + 16 + q4*4];
    const bf8_t k00 = *(const bf8_t*)&Ks[k00i];
    const bf8_t k01 = *(const bf8_t*)&Ks[k01i];
    const bf8_t k10 = *(const bf8_t*)&Ks[k10i];
    const bf8_t k11 = *(const bf8_t*)&Ks[k11i];
    f32x4_t st0 = (f32x4_t){0.f,0.f,0.f,0.f};
    f32x4_t st1 = (f32x4_t){0.f,0.f,0.f,0.f};
    st0 = __builtin_amdgcn_mfma_f32_16x16x32_bf16(k00, qf0, st0, 0,0,0);
    st0 = __builtin_amdgcn_mfma_f32_16x16x32_bf16(k01, qf1, st0, 0,0,0);
    st1 = __builtin_amdgcn_mfma_f32_16x16x32_bf16(k10, qf0, st1, 0,0,0);
    st1 = __builtin_amdgcn_mfma_f32_16x16x32_bf16(k11, qf1, st1, 0,0,0);

    f16x4_t vA0, vA1, vA2, vA3, vB0, vB1, vB2, vB3;
    asm volatile("ds_read_b64_tr_b16 %0, %1 offset:0"    : "=v"(vA0) : "v"(trb));
    asm volatile("ds_read_b64_tr_b16 %0, %1 offset:512"  : "=v"(vA1) : "v"(trb));
    asm volatile("ds_read_b64_tr_b16 %0, %1 offset:1024" : "=v"(vA2) : "v"(trb));
    asm volatile("ds_read_b64_tr_b16 %0, %1 offset:1536" : "=v"(vA3) : "v"(trb));
    asm volatile("ds_read_b64_tr_b16 %0, %1 offset:2048" : "=v"(vB0) : "v"(trb));
    asm volatile("ds_read_b64_tr_b16 %0, %1 offset:2560" : "=v"(vB1) : "v"(trb));
    asm volatile("ds_read_b64_tr_b16 %0, %1 offset:3072" : "=v"(vB2) : "v"(trb));
    asm volatile("ds_read_b64_tr_b16 %0, %1 offset:3584" : "=v"(vB3) : "v"(trb));

    f16x4_t pf0, pf1;
    #pragma unroll
    for (int r=0;r<4;r++){
      const float p = __builtin_exp2f(st0[r]*SC2_) * m0[r];
      lsum += p;
      pf0[r] = (_Float16)p;
    }
    #pragma unroll
    for (int r=0;r<4;r++){
      const float p = __builtin_exp2f(st1[r]*SC2_) * m1[r];
      lsum += p;
      pf1[r] = (_Float16)p;
    }

    asm volatile("s_waitcnt lgkmcnt(0)" ::: "memory");
    __builtin_amdgcn_sched_barrier(0);

    cacc[0] = __builtin_amdgcn_mfma_f32_16x16x16f16(pf0, vA0, cacc[0], 0,0,0);
    cacc[1] = __builtin_amdgcn_mfma_f32_16x16x16f16(pf0, vA1, cacc[1], 0,0,0);
    cacc[2] = __builtin_amdgcn_mfma_f32_16x16x16f16(pf0, vA2, cacc[2], 0,0,0);
    cacc[3] = __builtin_amdgcn_mfma_f32_16x16x16f16(pf0, vA3, cacc[3], 0,0,0);
    cacc[0] = __builtin_amdgcn_mfma_f32_16x16x16f16(pf1, vB0, cacc[0], 0,0,0);
    cacc[1] = __builtin_amdgcn_mfma_f32_16x16x16f16(pf1, vB1, cacc[1], 0,0,0);
    cacc[2] = __builtin_amdgcn_mfma_f32_16x16x16f16(pf1, vB2, cacc[2], 0,0,0);
    cacc[3] = __builtin_amdgcn_mfma_f32_16x16x16f16(pf1, vB3, cacc[3], 0,0,0);
  }

  lsum += __shfl_xor(lsum, 16);
  lsum += __shfl_xor(lsum, 32);
  #pragma unroll
  for (int r=0;r<4;r++){
    const int m2 = q4*4 + r;
    const float lr = __shfl(lsum, m2);
    const float inv = 1.0f/lr;
    const long orow = (long)(b*512 + qb*64 + w*16 + m2)*Dd + h*64;
    #pragma unroll
    for (int dblk=0; dblk<4; dblk++){
      ctx[orow + dblk*16 + mr] = f2bf(cacc[dblk][r]*inv);
    }
  }
}

// ---------------- ctxmean: mean over seq of ctx -> (e,b,d) fp32 ----------------
__global__ void ctxmean_kernel(const unsigned short* __restrict__ ctx, float* __restrict__ out){
  const int d = blockIdx.x*256 + threadIdx.x;
  const int b = blockIdx.y, e = blockIdx.z;
  const unsigned short* p = ctx + ((size_t)e*MROWS + b*512)*Dd + d;
  float s = 0.f;
  for (int i=0;i<512;i++) s += bf2f(p[(size_t)i*Dd]);
  out[((size_t)e*Bb + b)*Dd + d] = s * (1.0f/512.0f);
}

// ---------------- featgemm ----------------
__global__ __launch_bounds__(256)
void featgemm_kernel(const float* __restrict__ ctxmean, const unsigned short* __restrict__ Wdb,
                     const float* __restrict__ bd, float* __restrict__ feat){
  __shared__ float xs[Dd];
  const int b = blockIdx.x, e = blockIdx.y;
  const int t = threadIdx.x;
  for (int i=t;i<Dd;i+=256) xs[i] = ctxmean[((size_t)e*Bb+b)*Dd + i];
  __syncthreads();
  #pragma unroll
  for (int c0=0;c0<3;c0++){
    const int col = c0*256 + t;
    const unsigned short* wr = Wdb + ((size_t)e*Dd + col)*Dd;
    float s = 0.f;
    for (int k=0;k<Dd;k+=8){
      bf8_t wv = *(const bf8_t*)(wr + k);
      const unsigned short* wp = (const unsigned short*)&wv;
      #pragma unroll
      for (int j=0;j<8;j++) s += bf2f(wp[j]) * xs[k+j];
    }
    feat[((size_t)e*Bb+b)*Dd + col] = s + bd[(size_t)e*Dd + col];
  }
}

// ---------------- routing ----------------
__global__ void routing_kernel(const float* __restrict__ feat, const float* __restrict__ centers,
                               int* __restrict__ sel)
{
  __shared__ float d2s[64];
  const int t = threadIdx.x;
  if (t < 64){
    const int e = t>>3, b = t&7;
    const float* f = feat + (long)(e*Bb + b)*Dd;
    const float* c = centers + (long)e*Dd;
    float s = 0.f;
    for (int d=0; d<Dd; d++){
      const float df = f[d] - c[d];
      s += df*df;
    }
    d2s[t] = s;
  }
  __syncthreads();
  if (t < 8){
    float best = 3.4e38f; int bi = 0;
    for (int e=0;e<8;e++){ const float v = d2s[e*8+t]; if (v < best){ best=v; bi=e; } }
    sel[t] = bi;
  }
}

// ---------------- h = LN1(attsel+x) ----------------
__global__ __launch_bounds__(256)
void hprep_kernel(const unsigned short* __restrict__ attsel, const float* __restrict__ x,
                  const float* __restrict__ g, const float* __restrict__ be,
                  const int* __restrict__ sel, unsigned short* __restrict__ hbuf)
{
  const int w = threadIdx.x>>6, l = threadIdx.x&63;
  const int row = blockIdx.x*4 + w;
  const int b = row>>9;
  const int e = sel[b];
  const unsigned short* ap = attsel + (long)row*Dd;
  const float* xp = x + (long)row*Dd;
  float v[12]; float s = 0.f;
  #pragma unroll
  for (int i=0;i<12;i++){ const int d = i*64 + l; v[i] = bf2f(ap[d]) + xp[d]; s += v[i]; }
  #pragma unroll
  for (int o=32;o>0;o>>=1) s += __shfl_xor(s, o);
  const float mean = s * (1.0f/768.0f);
  float vs = 0.f;
  #pragma unroll
  for (int i=0;i<12;i++){ const float dd = v[i]-mean; vs += dd*dd; }
  #pragma unroll
  for (int o=32;o>0;o>>=1) vs += __shfl_xor(vs, o);
  const float rs = rsqrtf(vs*(1.0f/768.0f) + 1e-12f);
  #pragma unroll
  for (int i=0;i<12;i++){
    const int d = i*64 + l;
    hbuf[(long)row*Dd + d] = f2bf((v[i]-mean)*rs*g[(long)e*Dd+d] + be[(long)e*Dd+d]);
  }
}

// ---------------- out = LN2(h + ffn) ----------------
__global__ __launch_bounds__(256)
void ln2_kernel(const unsigned short* __restrict__ hbuf, const float* __restrict__ tbuf,
                const float* __restrict__ g, const float* __restrict__ be,
                const int* __restrict__ sel, float* __restrict__ out)
{
  const int w = threadIdx.x>>6, l = threadIdx.x&63;
  const int row = blockIdx.x*4 + w;
  const int b = row>>9;
  const int e = sel[b];
  const unsigned short* hp = hbuf + (long)row*Dd;
  const float* tp = tbuf + (long)row*Dd;
  float v[12]; float s = 0.f;
  #pragma unroll
  for (int i=0;i<12;i++){ const int d = i*64 + l; v[i] = bf2f(hp[d]) + tp[d]; s += v[i]; }
  #pragma unroll
  for (int o=32;o>0;o>>=1) s += __shfl_xor(s, o);
  const float mean = s * (1.0f/768.0f);
  float vs = 0.f;
  #pragma unroll
  for (int i=0;i<12;i++){ const float dd = v[i]-mean; vs += dd*dd; }
  #pragma unroll
  for (int o=32;o>0;o>>=1) vs += __shfl_xor(vs, o);
  const float rs = rsqrtf(vs*(1.0f/768.0f) + 1e-12f);
  #pragma unroll
  for (int i=0;i<12;i++){
    const int d = i*64 + l;
    out[(long)row*Dd + d] = (v[i]-mean)*rs*g[(long)e*Dd+d] + be[(long)e*Dd+d];
  }
}

// ---------------- launch ----------------
extern "C" void kernel_launch(void* const* d_in, const int* in_sizes, int n_in,
                              void* d_out, int out_size, void* d_ws, size_t ws_size,
                              hipStream_t stream)
{
  const float* x      = (const float*)d_in[0];
  const int*   mask   = (const int*)d_in[1];
  const float* Wqkv   = (const float*)d_in[2];
  const float* Wd     = (const float*)d_in[3];
  const float* bd     = (const float*)d_in[4];
  const float* ln1g   = (const float*)d_in[5];
  const float* ln1b   = (const float*)d_in[6];
  const float* W1     = (const float*)d_in[7];
  const float* b1     = (const float*)d_in[8];
  const float* W2     = (const float*)d_in[9];
  const float* b2     = (const float*)d_in[10];
  const float* ln2g   = (const float*)d_in[11];
  const float* ln2b   = (const float*)d_in[12];
  const float* centers= (const float*)d_in[13];

  hipFuncSetAttribute((const void*)gemm8p, hipFuncAttributeMaxDynamicSharedMemorySize, 131072);

  int zc;
  if      (ws_size >= 258347264ull) zc = 8;
  else if (ws_size >= 182849792ull) zc = 4;
  else if (ws_size >= 145101056ull) zc = 2;
  else                              zc = 1;

  char* p = (char*)d_ws;
  auto carve = [&](size_t bytes)->char*{ char* r = p; p += ((bytes + 255) & ~(size_t)255); return r; };

  unsigned short* xb      = (unsigned short*)carve((size_t)MROWS*Dd*2);
  unsigned short* Wqkvb   = (unsigned short*)carve((size_t)Ee*QKVN*Dd*2);
  unsigned short* Wdb     = (unsigned short*)carve((size_t)Ee*Dd*Dd*2);
  float*          ctxmean = (float*)carve((size_t)Ee*Bb*Dd*4);
  float*          feat    = (float*)carve((size_t)Ee*Bb*Dd*4);
  int*            sel     = (int*)carve(256);
  unsigned short* hbuf    = (unsigned short*)carve((size_t)MROWS*Dd*2);
  unsigned short* attsel  = (unsigned short*)carve((size_t)MROWS*Dd*2);
  unsigned short* qkvchk  = (unsigned short*)carve((size_t)zc*MROWS*QKVN*2);
  unsigned short* ctx_all = (unsigned short*)carve((size_t)Ee*MROWS*Dd*2);
  unsigned short* Gbuf = attsel;          // FFN1 out: 25.2 MB over attsel + first 18.9 MB of qkvchk
  float*          tbuf = (float*)ctx_all; // FFN2 out: 12.6 MB over ctx_all (dead)
  // bf16 weight stash (zc==8 only): inside qkvchk, past Gbuf's 18.9 MB overlap.
  // W1b 37.75 MB + W2b 37.75 MB ends at qkvchk+94.4 MB <= 151 MB region.
  unsigned short* W1b = (unsigned short*)((char*)qkvchk + 18874368);
  unsigned short* W2b = (unsigned short*)((char*)W1b + (size_t)Ee*DFF*Dd*2);
  const bool fastFFN = (zc == 8);

  cast_kernel<<<(MROWS*Dd/4 + 255)/256, 256, 0, stream>>>(x, xb, MROWS*Dd);
  cast_kernel<<<(Ee*QKVN*Dd/4 + 255)/256, 256, 0, stream>>>(Wqkv, Wqkvb, Ee*QKVN*Dd);
  cast_kernel<<<(Ee*Dd*Dd/4 + 255)/256, 256, 0, stream>>>(Wd, Wdb, Ee*Dd*Dd);

  const int nchunk = Ee / zc;
  for (int c = 0; c < nchunk; c++){
    gemm8p<<<dim3(QKVN/256, MROWS/256, zc), 512, 131072, stream>>>(
        xb, Wqkvb + (size_t)c*zc*QKVN*Dd, qkvchk,
        Dd, QKVN, (long)QKVN*Dd, (long)MROWS*QKVN, (zc==8) ? 1 : 0);
    attn_kernel<<<dim3(8, Hh, Bb*zc), 256, 0, stream>>>(
        qkvchk, mask, ctx_all + (size_t)c*zc*MROWS*Dd,
        (long)MROWS*QKVN, (long)MROWS*Dd, (zc==8) ? 1 : 0);
    ctxmean_kernel<<<dim3(3, Bb, zc), 256, 0, stream>>>(
        ctx_all + (size_t)c*zc*MROWS*Dd, ctxmean + (size_t)c*zc*Bb*Dd);
  }

  featgemm_kernel<<<dim3(Bb, Ee), 256, 0, stream>>>(ctxmean, Wdb, bd, feat);
  routing_kernel<<<1, 64, 0, stream>>>(feat, centers, sel);

  if (fastFFN){
    // qkvchk dead after the attn loop; cast selected experts' FFN weights to bf16
    castsel_kernel<<<dim3((DFF*Dd/4 + 255)/256, 1, Ee), 256, 0, stream>>>(W1, W1b, DFF*Dd, sel);
    castsel_kernel<<<dim3((Dd*DFF/4 + 255)/256, 1, Ee), 256, 0, stream>>>(W2, W2b, Dd*DFF, sel);
  }

  gemm_bt<1><<<dim3(Dd/128, MROWS/128, 1), 256, 0, stream>>>(
      ctx_all, Wdb, nullptr, bd, attsel, Dd, Dd, 0, 0,
      sel, (long)MROWS*Dd, (long)Dd*Dd, Dd, 2);

  hprep_kernel<<<MROWS/4, 256, 0, stream>>>(attsel, x, ln1g, ln1b, sel, hbuf);

  if (fastFFN){
    gemm_bt<4><<<dim3(DFF/128, MROWS/128, 1), 256, 0, stream>>>(
        hbuf, W1b, nullptr, b1, Gbuf, Dd, DFF, 0, 0,
        sel, 0, (long)DFF*Dd, DFF, 2);
    gemm_bt<5><<<dim3(Dd/128, MROWS/128, 1), 256, 0, stream>>>(
        Gbuf, W2b, nullptr, b2, tbuf, DFF, Dd, 0, 0,
        sel, 0, (long)Dd*DFF, Dd, 2);
  } else {
    gemm_bt<2><<<dim3(DFF/128, MROWS/128, 1), 256, 0, stream>>>(
        hbuf, nullptr, W1, b1, Gbuf, Dd, DFF, 0, 0,
        sel, 0, (long)DFF*Dd, DFF, 2);
    gemm_bt<3><<<dim3(Dd/128, MROWS/128, 1), 256, 0, stream>>>(
        Gbuf, nullptr, W2, b2, tbuf, DFF, Dd, 0, 0,
        sel, 0, (long)Dd*DFF, Dd, 2);
  }
  ln2_kernel<<<MROWS/4, 256, 0, stream>>>(hbuf, tbuf, ln2g, ln2b, sel, (float*)d_out);
}